// Round 6
// baseline (436.004 us; speedup 1.0000x reference)
//
#include <hip/hip_runtime.h>
#include <math.h>

#define PLANE 16384
#define NTOT  33554432u
#define TP    136            // LDS row pitch in shorts: 272B = 17*16B -> 2-way max
typedef unsigned int  uint;
typedef unsigned short ushort;

typedef __attribute__((ext_vector_type(8))) short  short8;
typedef __attribute__((ext_vector_type(8))) ushort ushort8;
typedef __attribute__((ext_vector_type(4))) ushort bf16x4;
typedef __attribute__((ext_vector_type(4))) uint   u32x4;
typedef __attribute__((ext_vector_type(4))) float  f32x4;

__device__ __forceinline__ ushort f2bf(float x){
  unsigned u = __float_as_uint(x);
  u = (u + 0x7FFFu + ((u >> 16) & 1u)) >> 16;
  return (ushort)u;
}
__device__ __forceinline__ float bf2f(ushort h){
  return __uint_as_float(((uint)h) << 16);
}
__device__ __forceinline__ uint pk(float a, float b){
  return (uint)f2bf(a) | ((uint)f2bf(b) << 16);
}

// Generate 128x128 bf16 DFT twiddle table into LDS (pitch TP).
// SGN=-1: fwd exp(-i 2pi nk/128); SGN=+1: inverse exp(+i 2pi nk/128).
template<int SGN>
__device__ __forceinline__ void gen_table(ushort* Fre, ushort* Fim, int t){
  int n = t >> 2, kb = (t & 3) * 32;
  #pragma unroll
  for(int q=0; q<4; q++){
    ushort8 cv, sv;
    #pragma unroll
    for(int j=0; j<8; j++){
      int k = kb + q*8 + j;
      int idx = (n*k) & 127;
      float ss, cc;
      __sincosf((float)idx * 0.049087385212340517f, &ss, &cc);  // 2pi/128
      cv[j] = f2bf(cc);
      sv[j] = f2bf(SGN < 0 ? -ss : ss);
    }
    *(ushort8*)(&Fre[n*TP + kb + q*8]) = cv;
    *(ushort8*)(&Fim[n*TP + kb + q*8]) = sv;
  }
}

// ---------------- kernel 0: fold BN, emit MFMA-fragment-packed bf16 weights --
// wb layout: shorts [0,32768)     = w1p B-frags: [(et*4+kt)*64 + l]*8 + j
//            shorts [32768,65536) = w2p A-frags: [(ot*8+kt)*64 + l]*8 + j
//            floats [32768,33024) = c1[256]; floats [33024,33152) = c2[128]
__global__ __launch_bounds__(256) void k_prep(
    const float* __restrict__ w1, const float* __restrict__ b1,
    const float* __restrict__ g1, const float* __restrict__ be1,
    const float* __restrict__ m1, const float* __restrict__ v1,
    const float* __restrict__ w2, const float* __restrict__ b2,
    const float* __restrict__ g2, const float* __restrict__ be2,
    const float* __restrict__ m2, const float* __restrict__ v2,
    float* __restrict__ wb){
  int g = blockIdx.x*256 + threadIdx.x;      // 65536 threads
  ushort* wbs = (ushort*)wb;
  if(g < 32768){
    int kt = (g >> 9) & 3, l = (g >> 3) & 63, j = g & 7;
    int et = g >> 11;
    int c = kt*32 + 8*(l>>4) + j;
    int e = et*16 + (l&15);
    float s1 = g1[e]*rsqrtf(v1[e]+1e-5f);
    wbs[g] = f2bf(w1[e*128 + c]*s1);
  } else {
    int g2i = g - 32768;
    int ot = g2i >> 12, kt = (g2i >> 9) & 7, l = (g2i >> 3) & 63, j = g2i & 7;
    int o = ot*16 + (l&15);
    int e = kt*32 + 8*(l>>4) + j;
    float s2 = g2[o]*rsqrtf(v2[o]+1e-5f);
    wbs[32768 + g2i] = f2bf(w2[o*256 + e]*s2);
  }
  if(g < 256){
    float s1 = g1[g]*rsqrtf(v1[g]+1e-5f);
    wb[32768 + g] = b1[g]*s1 + be1[g] - m1[g]*s1;
  }
  if(g < 128){
    float s2 = g2[g]*rsqrtf(v2[g]+1e-5f);
    wb[33024 + g] = b2[g]*s2 + be2[g] - m2[g]*s2;
  }
}

// ---------------- kernel 1: forward 2D DFT via MFMA + fftshift + HPF ---------
// spec[b'][c'][wd][hd] = masked shifted 2D fwd DFT (ortho 1/128 folded here).
// Step A: P[h][wd] = sum_w x[h][w] * F[wd^64][w]   (real input, strip-streamed)
// Step B: S[wd][hd] = sum_h P[h][wd] * F[hd^64][h]
__global__ __launch_bounds__(512,1) void k_fft_fwd(const float* __restrict__ x2,
                                                   uint* __restrict__ spec){
  __shared__ ushort Fre[128*TP], Fim[128*TP];
  __shared__ ushort Pre[128*TP], Pim[128*TP];   // P stored [wd][h]
  __shared__ ushort xb[2][16*TP];
  int t = threadIdx.x, l = t & 63, wv = t >> 6;
  int bid = blockIdx.x, b = bid >> 7, c = bid & 127;
  const float* src = x2 + (size_t)(b*128 + c)*PLANE;
  gen_table<-1>(Fre, Fim, t);
  int hr = t >> 5, c4 = (t & 31)*4;
  { // stage strip 0
    f32x4 v = *(const f32x4*)(src + hr*128 + c4);
    bf16x4 o;
    #pragma unroll
    for(int j=0;j<4;j++) o[j] = f2bf(v[j]);
    *(bf16x4*)(&xb[0][hr*TP + c4]) = o;
  }
  __syncthreads();
  int koff = 8*(l >> 4);
  for(int s=0; s<8; s++){
    f32x4 pf;
    if(s < 7) pf = *(const f32x4*)(src + (16*(s+1) + hr)*128 + c4);
    // step A tile: wave wv -> wd col-tile [16wv,16wv+16), rows h in strip
    int arow = (l & 15)*TP;
    int brow = (16*(wv ^ 4) + (l & 15))*TP;     // ^64 shift baked as tile^4
    f32x4 pr = {0,0,0,0}, pi = {0,0,0,0};
    #pragma unroll
    for(int kt=0; kt<4; kt++){
      short8 xa = *(const short8*)(&xb[s&1][arow + kt*32 + koff]);
      short8 fr = *(const short8*)(&Fre[brow + kt*32 + koff]);
      short8 fi = *(const short8*)(&Fim[brow + kt*32 + koff]);
      pr = __builtin_amdgcn_mfma_f32_16x16x32_bf16(xa, fr, pr, 0,0,0);
      pi = __builtin_amdgcn_mfma_f32_16x16x32_bf16(xa, fi, pi, 0,0,0);
    }
    int wd = 16*wv + (l & 15);
    int hb = 16*s + 4*(l >> 4);
    bf16x4 pr4, pi4;
    #pragma unroll
    for(int r=0;r<4;r++){ pr4[r] = f2bf(pr[r]); pi4[r] = f2bf(pi[r]); }
    *(bf16x4*)(&Pre[wd*TP + hb]) = pr4;
    *(bf16x4*)(&Pim[wd*TP + hb]) = pi4;
    if(s < 7){
      bf16x4 o;
      #pragma unroll
      for(int j=0;j<4;j++) o[j] = f2bf(pf[j]);
      *(bf16x4*)(&xb[(s+1)&1][hr*TP + c4]) = o;
    }
    __syncthreads();
  }
  // step B: wave wv owns wd-strip [16wv,16wv+16)
  int bp = (b + 8) & 15, cp = (c + 64) & 127;
  uint* dst = spec + (size_t)(bp*128 + cp)*PLANE;
  int arow2 = (16*wv + (l & 15))*TP;
  short8 ar[4], ai[4];
  #pragma unroll
  for(int kt=0; kt<4; kt++){
    ar[kt] = *(const short8*)(&Pre[arow2 + kt*32 + koff]);
    ai[kt] = *(const short8*)(&Pim[arow2 + kt*32 + koff]);
  }
  const float SC = 1.0f/128.0f;
  uint* tw = ((uint*)xb) + wv*256;             // per-wave 16x16 scratch (xb dead)
  #pragma unroll
  for(int ct=0; ct<8; ct++){
    int brow = (16*(ct ^ 4) + (l & 15))*TP;     // hd^64 shift baked
    f32x4 sr_ = {0,0,0,0}, si_ = {0,0,0,0};
    #pragma unroll
    for(int kt=0; kt<4; kt++){
      short8 fi = *(const short8*)(&Fim[brow + kt*32 + koff]);
      sr_ = __builtin_amdgcn_mfma_f32_16x16x32_bf16(ai[kt], fi, sr_, 0,0,0);
      si_ = __builtin_amdgcn_mfma_f32_16x16x32_bf16(ar[kt], fi, si_, 0,0,0);
    }
    sr_ = -sr_;                                  // -> -sum Pim*Fim
    #pragma unroll
    for(int kt=0; kt<4; kt++){
      short8 fr = *(const short8*)(&Fre[brow + kt*32 + koff]);
      sr_ = __builtin_amdgcn_mfma_f32_16x16x32_bf16(ar[kt], fr, sr_, 0,0,0);
      si_ = __builtin_amdgcn_mfma_f32_16x16x32_bf16(ai[kt], fr, si_, 0,0,0);
    }
    int hd0 = 16*ct;
    {
      int hd = hd0 + (l & 15);
      float dh = (float)hd - 63.5f;
      float dh2 = dh*dh;
      #pragma unroll
      for(int r=0; r<4; r++){
        int wd = 16*wv + 4*(l>>4) + r;
        float dw = (float)wd - 63.5f;
        float m = (dw*dw + dh2 >= 64.0f) ? SC : 0.0f;
        tw[(4*(l>>4)+r)*16 + (l&15)] = pk(sr_[r]*m, si_[r]*m);
      }
    }
    // transposed vector store: lane -> 4 consecutive hd of one wd row
    u32x4 v4 = *(u32x4*)(tw + (l>>2)*16 + (l&3)*4);
    *(u32x4*)(dst + (16*wv + (l>>2))*128 + hd0 + (l&3)*4) = v4;
  }
}

// ---------------- kernel 2: fused 1x1conv chain via bf16 MFMA ----------------
#define XPITCH 136
#define EPITCH 264
__global__ __launch_bounds__(256,3) void k_conv(const float* __restrict__ wb,
                                                const uint* __restrict__ spec,
                                                uint* __restrict__ zo){
  __shared__ ushort xs[64*XPITCH];
  __shared__ ushort hs[64*EPITCH];
  const ushort* wbs = (const ushort*)wb;
  int bid = blockIdx.x;
  int b = bid >> 9;
  int pix0 = (bid & 511) * 32;
  const uint* sp = spec + (size_t)(b*128)*PLANE + pix0;
  int t = threadIdx.x, l = t & 63, w = t >> 6;
  {
    int p = t & 31, g = t >> 5;
    #pragma unroll
    for(int half=0; half<2; half++){
      ushort re8[8], im8[8];
      #pragma unroll
      for(int k=0;k<8;k++){
        uint u = sp[(size_t)(g*16 + half*8 + k)*PLANE + p];
        re8[k] = (ushort)u; im8[k] = (ushort)(u>>16);
      }
      *(ushort8*)(xs + p*XPITCH      + g*16 + half*8) = *(ushort8*)re8;
      *(ushort8*)(xs + (p+32)*XPITCH + g*16 + half*8) = *(ushort8*)im8;
    }
  }
  short8 bw1[4][4];
  #pragma unroll
  for(int et=0; et<4; et++)
    #pragma unroll
    for(int kt=0; kt<4; kt++)
      bw1[et][kt] = *(const short8*)(wbs + (((w*4+et)*4 + kt)*64 + l)*8);
  float c1v[4];
  #pragma unroll
  for(int et=0; et<4; et++) c1v[et] = wb[32768 + w*64 + et*16 + (l&15)];
  __syncthreads();
  #pragma unroll
  for(int mt=0; mt<4; mt++){
    short8 xa[4];
    #pragma unroll
    for(int kt=0; kt<4; kt++)
      xa[kt] = *(const short8*)(xs + (mt*16 + (l&15))*XPITCH + kt*32 + 8*(l>>4));
    f32x4 a0 = {0,0,0,0}, a1 = {0,0,0,0}, a2 = {0,0,0,0}, a3 = {0,0,0,0};
    #pragma unroll
    for(int kt=0; kt<4; kt++){
      a0 = __builtin_amdgcn_mfma_f32_16x16x32_bf16(xa[kt], bw1[0][kt], a0, 0,0,0);
      a1 = __builtin_amdgcn_mfma_f32_16x16x32_bf16(xa[kt], bw1[1][kt], a1, 0,0,0);
      a2 = __builtin_amdgcn_mfma_f32_16x16x32_bf16(xa[kt], bw1[2][kt], a2, 0,0,0);
      a3 = __builtin_amdgcn_mfma_f32_16x16x32_bf16(xa[kt], bw1[3][kt], a3, 0,0,0);
    }
    #pragma unroll
    for(int et=0; et<4; et++){
      f32x4 av = et==0?a0 : et==1?a1 : et==2?a2 : a3;
      #pragma unroll
      for(int r=0; r<4; r++){
        float h = fmaxf(av[r] + c1v[et], 0.f);
        hs[(mt*16 + (l>>4)*4 + r)*EPITCH + w*64 + et*16 + (l&15)] = f2bf(h);
      }
    }
  }
  short8 aw2[2][8];
  #pragma unroll
  for(int ot=0; ot<2; ot++)
    #pragma unroll
    for(int kt=0; kt<8; kt++)
      aw2[ot][kt] = *(const short8*)(wbs + 32768 + (((w*2+ot)*8 + kt)*64 + l)*8);
  float c2r[8];
  #pragma unroll
  for(int ot=0; ot<2; ot++)
    #pragma unroll
    for(int r=0; r<4; r++)
      c2r[ot*4+r] = wb[33024 + w*32 + ot*16 + (l>>4)*4 + r];
  __syncthreads();
  f32x4 d[2][4];
  #pragma unroll
  for(int ot=0; ot<2; ot++)
    #pragma unroll
    for(int pt=0; pt<4; pt++) d[ot][pt] = (f32x4){0,0,0,0};
  for(int kt=0; kt<8; kt++){
    short8 hb[4];
    #pragma unroll
    for(int pt=0; pt<4; pt++)
      hb[pt] = *(const short8*)(hs + (pt*16 + (l&15))*EPITCH + kt*32 + 8*(l>>4));
    #pragma unroll
    for(int ot=0; ot<2; ot++)
      #pragma unroll
      for(int pt=0; pt<4; pt++)
        d[ot][pt] = __builtin_amdgcn_mfma_f32_16x16x32_bf16(aw2[ot][kt], hb[pt], d[ot][pt], 0,0,0);
  }
  uint* zb = zo + (size_t)(b*128)*PLANE + pix0;
  #pragma unroll
  for(int ot=0; ot<2; ot++){
    #pragma unroll
    for(int pp=0; pp<2; pp++){
      #pragma unroll
      for(int r=0; r<4; r++){
        int o = w*32 + ot*16 + (l>>4)*4 + r;
        int p = pp*16 + (l&15);
        float re = d[ot][pp][r]   + c2r[ot*4+r] + bf2f(xs[p*XPITCH + o]);
        float im = d[ot][pp+2][r] + c2r[ot*4+r] + bf2f(xs[(p+32)*XPITCH + o]);
        zb[(size_t)o*PLANE + p] = pk(re, im);
      }
    }
  }
}

// ---------------- kernel 3: inverse 2D DFT via MFMA + |.| + outputs ----------
// z[wd][hd] bf16 packed (aliases out+2*NTOT, plane-aligned).
// Step A: T[wd][nh] = sum_hd Z[wd][hd] * G[nh][hd]   (strip-streamed over wd)
// Step B: S[nh][nw] = sum_wd T[wd][nh] * G[nw][wd];  h = |S| / 128
__global__ __launch_bounds__(512,1) void k_ifft_out(const uint* z,
                                                    const float* __restrict__ xin1,
                                                    const float* __restrict__ xin2,
                                                    float* out){
  __shared__ ushort Gre[128*TP], Gim[128*TP];
  __shared__ ushort Tre[128*TP], Tim[128*TP];   // T stored [nh][wd]
  __shared__ ushort zbb[4][16*TP];              // [0,1]=re dbuf, [2,3]=im dbuf
  int t = threadIdx.x, l = t & 63, wv = t >> 6;
  int bid = blockIdx.x, b = bid >> 7, o = bid & 127;
  size_t plane = (size_t)(b*128 + o)*PLANE;
  const uint* zp = z + plane;
  gen_table<1>(Gre, Gim, t);
  int rr = t >> 5, c4 = (t & 31)*4;
  { // stage strip 0 (wd rows 0..15)
    u32x4 u = *(const u32x4*)(zp + rr*128 + c4);
    bf16x4 ur, ui;
    #pragma unroll
    for(int j=0;j<4;j++){ ur[j] = (ushort)u[j]; ui[j] = (ushort)(u[j]>>16); }
    *(bf16x4*)(&zbb[0][rr*TP + c4]) = ur;
    *(bf16x4*)(&zbb[2][rr*TP + c4]) = ui;
  }
  __syncthreads();
  int koff = 8*(l >> 4);
  for(int s=0; s<8; s++){
    u32x4 pf;
    if(s < 7) pf = *(const u32x4*)(zp + (16*(s+1) + rr)*128 + c4);
    // step A tile: wave wv -> nh col-tile [16wv,+16), rows wd in strip
    int arow = (l & 15)*TP;
    int brow = (16*wv + (l & 15))*TP;
    short8 zr[4], zi[4], gr[4], gi[4];
    #pragma unroll
    for(int kt=0; kt<4; kt++){
      zr[kt] = *(const short8*)(&zbb[s&1][arow + kt*32 + koff]);
      zi[kt] = *(const short8*)(&zbb[2+(s&1)][arow + kt*32 + koff]);
      gr[kt] = *(const short8*)(&Gre[brow + kt*32 + koff]);
      gi[kt] = *(const short8*)(&Gim[brow + kt*32 + koff]);
    }
    f32x4 tr = {0,0,0,0}, ti = {0,0,0,0};
    #pragma unroll
    for(int kt=0; kt<4; kt++) tr = __builtin_amdgcn_mfma_f32_16x16x32_bf16(zi[kt], gi[kt], tr, 0,0,0);
    tr = -tr;                                    // -> -sum Zim*Gim
    #pragma unroll
    for(int kt=0; kt<4; kt++) tr = __builtin_amdgcn_mfma_f32_16x16x32_bf16(zr[kt], gr[kt], tr, 0,0,0);
    #pragma unroll
    for(int kt=0; kt<4; kt++){
      ti = __builtin_amdgcn_mfma_f32_16x16x32_bf16(zr[kt], gi[kt], ti, 0,0,0);
      ti = __builtin_amdgcn_mfma_f32_16x16x32_bf16(zi[kt], gr[kt], ti, 0,0,0);
    }
    int nh = 16*wv + (l & 15);
    int wdb = 16*s + 4*(l >> 4);
    bf16x4 t4r, t4i;
    #pragma unroll
    for(int r=0;r<4;r++){ t4r[r] = f2bf(tr[r]); t4i[r] = f2bf(ti[r]); }
    *(bf16x4*)(&Tre[nh*TP + wdb]) = t4r;
    *(bf16x4*)(&Tim[nh*TP + wdb]) = t4i;
    if(s < 7){
      bf16x4 ur, ui;
      #pragma unroll
      for(int j=0;j<4;j++){ ur[j] = (ushort)pf[j]; ui[j] = (ushort)(pf[j]>>16); }
      *(bf16x4*)(&zbb[(s+1)&1][rr*TP + c4]) = ur;
      *(bf16x4*)(&zbb[2+((s+1)&1)][rr*TP + c4]) = ui;
    }
    __syncthreads();
  }
  // step B: wave wv owns nh-strip [16wv,+16)
  int arow2 = (16*wv + (l & 15))*TP;
  short8 ar[4], ai[4];
  #pragma unroll
  for(int kt=0; kt<4; kt++){
    ar[kt] = *(const short8*)(&Tre[arow2 + kt*32 + koff]);
    ai[kt] = *(const short8*)(&Tim[arow2 + kt*32 + koff]);
  }
  const float SC = 1.0f/128.0f;
  float* hw = ((float*)zbb) + wv*320;           // per-wave 16x20 f32 scratch (zbb dead)
  #pragma unroll
  for(int ct=0; ct<8; ct++){
    int brow = (16*ct + (l & 15))*TP;
    f32x4 sr_ = {0,0,0,0}, si_ = {0,0,0,0};
    #pragma unroll
    for(int kt=0; kt<4; kt++){
      short8 gi = *(const short8*)(&Gim[brow + kt*32 + koff]);
      sr_ = __builtin_amdgcn_mfma_f32_16x16x32_bf16(ai[kt], gi, sr_, 0,0,0);
      si_ = __builtin_amdgcn_mfma_f32_16x16x32_bf16(ar[kt], gi, si_, 0,0,0);
    }
    sr_ = -sr_;                                  // -> -sum Tim*Gim
    #pragma unroll
    for(int kt=0; kt<4; kt++){
      short8 gr = *(const short8*)(&Gre[brow + kt*32 + koff]);
      sr_ = __builtin_amdgcn_mfma_f32_16x16x32_bf16(ar[kt], gr, sr_, 0,0,0);
      si_ = __builtin_amdgcn_mfma_f32_16x16x32_bf16(ai[kt], gr, si_, 0,0,0);
    }
    #pragma unroll
    for(int r=0; r<4; r++)
      hw[(4*(l>>4)+r)*20 + (l&15)] = sqrtf(sr_[r]*sr_[r] + si_[r]*si_[r]) * SC;
    // transposed vector IO: lane -> 4 consecutive nw of one nh row
    f32x4 h4 = *(f32x4*)(hw + (l>>2)*20 + (l&3)*4);
    size_t idx4 = plane + (size_t)(16*wv + (l>>2))*128 + 16*ct + (l&3)*4;
    f32x4 u = *(const f32x4*)(xin1 + idx4);
    f32x4 v = *(const f32x4*)(xin2 + idx4);
    f32x4 o1, o2;
    #pragma unroll
    for(int j=0;j<4;j++){ o1[j] = u[j]*h4[j] + u[j]; o2[j] = v[j]*h4[j] + v[j]; }
    *(f32x4*)(out + idx4) = o1;
    *(f32x4*)(out + NTOT + idx4) = o2;
    *(f32x4*)(out + 2u*NTOT + idx4) = h4;
  }
}

extern "C" void kernel_launch(void* const* d_in, const int* in_sizes, int n_in,
                              void* d_out, int out_size, void* d_ws, size_t ws_size,
                              hipStream_t stream){
  (void)in_sizes; (void)n_in; (void)d_ws; (void)ws_size; (void)out_size;
  const float* x1  = (const float*)d_in[0];
  const float* x2  = (const float*)d_in[1];
  const float* w1  = (const float*)d_in[2];
  const float* b1  = (const float*)d_in[3];
  const float* g1  = (const float*)d_in[4];
  const float* be1 = (const float*)d_in[5];
  const float* m1  = (const float*)d_in[6];
  const float* v1  = (const float*)d_in[7];
  const float* w2  = (const float*)d_in[8];
  const float* b2  = (const float*)d_in[9];
  const float* g2  = (const float*)d_in[10];
  const float* be2 = (const float*)d_in[11];
  const float* m2  = (const float*)d_in[12];
  const float* v2  = (const float*)d_in[13];
  float* out = (float*)d_out;
  float* wb   = out;                       // slot0: weights (dead after conv)
  uint*  spec = (uint*)(out + NTOT);       // slot1: bf16 spectrum (dead after conv)
  uint*  z    = (uint*)(out + 2u*NTOT);    // slot2: bf16 z, plane-aliased with hx
  hipLaunchKernelGGL(k_prep,     dim3(256),  dim3(256), 0, stream,
                     w1,b1,g1,be1,m1,v1,w2,b2,g2,be2,m2,v2, wb);
  hipLaunchKernelGGL(k_fft_fwd,  dim3(2048), dim3(512), 0, stream, x2, spec);
  hipLaunchKernelGGL(k_conv,     dim3(8192), dim3(256), 0, stream, wb, spec, z);
  hipLaunchKernelGGL(k_ifft_out, dim3(2048), dim3(512), 0, stream, z, x1, x2, out);
}